// Round 10
// baseline (714.430 us; speedup 1.0000x reference)
//
#include <hip/hip_runtime.h>
#include <math.h>

// ---------------- problem constants ----------------
#define TLEN   64000
#define ECH    256
#define DCH    512
#define NBLK   2
#define NLAY   6
#define FKC    20
#define STRIDE_ 10
#define TC     6403            // encoder output length
#define NS     12928           // padded row count = 101*128 (n = b*TC + tc)
#define NTILE  101             // NS / 128
#define EPSV   1e-5f

typedef __attribute__((ext_vector_type(8))) short          s8v;
typedef __attribute__((ext_vector_type(4))) float          f4v;
typedef __attribute__((ext_vector_type(4))) unsigned short u4v;
typedef __attribute__((ext_vector_type(8))) unsigned short u8v;

__device__ __forceinline__ unsigned short f2bf(float f) {
    union { float f; unsigned u; } v; v.f = f;
    unsigned r = v.u + 0x7FFFu + ((v.u >> 16) & 1u);   // RNE
    return (unsigned short)(r >> 16);
}
__device__ __forceinline__ float bf2f(unsigned short h) {
    union { unsigned u; float f; } v; v.u = ((unsigned)h) << 16; return v.f;
}

// =====================================================================
// Weight convert fp32 -> bf16 (verified)
// =====================================================================
#define NWQ (12*512*256/4)      // float4 count per tensor = 393216
__global__ __launch_bounds__(256)
void wcvt_k(const float* __restrict__ w1, const float* __restrict__ w2,
            unsigned short* __restrict__ w1b, unsigned short* __restrict__ w2b)
{
    int i = blockIdx.x * 256 + threadIdx.x;
    if (i < NWQ) {
        float4 v = ((const float4*)w1)[i];
        u4v o = { f2bf(v.x), f2bf(v.y), f2bf(v.z), f2bf(v.w) };
        ((u4v*)w1b)[i] = o;
    } else {
        int j = i - NWQ;
        float4 v = ((const float4*)w2)[j];
        u4v o = { f2bf(v.x), f2bf(v.y), f2bf(v.z), f2bf(v.w) };
        ((u4v*)w2b)[j] = o;
    }
}

// =====================================================================
// Encoder -> bf16 [N][E] directly (verified)
// =====================================================================
__global__ __launch_bounds__(256)
void encoder_k(const float* __restrict__ x, const float* __restrict__ ew,
               const float* __restrict__ eb,
               unsigned short* __restrict__ EncB, unsigned short* __restrict__ Hb)
{
    __shared__ float xs[660];
    const int bx  = blockIdx.x;      // 0..100
    const int b   = blockIdx.y;      // 0..1
    const int tc0 = bx * 64;
    const int base_g = tc0 * STRIDE_ - FKC;
    for (int i = threadIdx.x; i < 660; i += 256) {
        int idx = base_g + i;
        xs[i] = (idx >= 0 && idx < TLEN) ? x[b * TLEN + idx] : 0.f;
    }
    __syncthreads();

    const int e = threadIdx.x;
    float w[20];
    #pragma unroll
    for (int q = 0; q < 5; ++q) {
        float4 v = *(const float4*)&ew[e * 20 + q * 4];
        w[q*4+0] = v.x; w[q*4+1] = v.y; w[q*4+2] = v.z; w[q*4+3] = v.w;
    }
    const float bz = eb[e];
    const int jmax = (TC - tc0 < 64) ? (TC - tc0) : 64;
    for (int j = 0; j < jmax; ++j) {
        const float* xp = &xs[j * 10];
        float acc = bz;
        #pragma unroll
        for (int k = 0; k < 20; ++k) acc = fmaf(xp[k], w[k], acc);
        unsigned short hv = f2bf(acc);
        size_t o = (size_t)(b * TC + tc0 + j) * 256 + e;
        EncB[o] = hv;
        Hb[o]   = hv;
    }
}

// =====================================================================
// bf16 MFMA GEMM, 64x128 tile (occupancy fix), reg-staged + prefetch:
//   acc[n][m] = sum_k W[m][k] * Act[n][k];  Out bf16 [NS][MOUT]
// 4 waves as 2x2 -> wave tile 32(M) x 64(N) = 2x4 frags 16x16x32.
// Grid: (NS/128) x (M/64)  -> conv1 808 blocks, conv2 404 blocks.
// EPI 0: bias+PReLU+BN | 1: bias | 2: bias+resid (in-place safe)
// =====================================================================
#define LROW 40

template<int KD, int MOUT, int EPI>
__global__ __launch_bounds__(256)
void gemm_bf16_k(const unsigned short* __restrict__ Wb,
                 const unsigned short* __restrict__ Act,
                 unsigned short* __restrict__ OutB,
                 const float* __restrict__ bias,
                 const float* __restrict__ alpha,
                 const float* __restrict__ gamma,
                 const float* __restrict__ beta,
                 const float* __restrict__ mean,
                 const float* __restrict__ var,
                 const unsigned short* __restrict__ Resid)
{
    __shared__ short At[64 * LROW];    // [m][k]
    __shared__ short Bt[128 * LROW];   // [n][k]

    const int t    = threadIdx.x;
    const int lane = t & 63;
    const int wid  = t >> 6;
    const int wm   = wid >> 1, wn = wid & 1;      // 2x2 wave grid
    const int r16  = lane & 15, g = lane >> 4;
    const int mb   = blockIdx.y * 64;
    const int nb   = blockIdx.x * 128;

    const int arow = t >> 2;            // 0..63
    const int kc8  = (t & 3) * 8;       // short offset within 32-k row

    const unsigned short* pA0 = &Wb[(size_t)(mb + arow)       * KD + kc8];
    const unsigned short* pB0 = &Act[(size_t)(nb + arow)      * KD + kc8];
    const unsigned short* pB1 = &Act[(size_t)(nb + arow + 64) * KD + kc8];

    f4v acc[2][4];
    #pragma unroll
    for (int a = 0; a < 2; ++a)
        #pragma unroll
        for (int c = 0; c < 4; ++c)
            acc[a][c] = (f4v){0.f, 0.f, 0.f, 0.f};

    constexpr int NSTEP = KD / 32;
    s8v a0 = *(const s8v*)(pA0);
    s8v b0 = *(const s8v*)(pB0);
    s8v b1 = *(const s8v*)(pB1);

    for (int s = 0; s < NSTEP; ++s) {
        __syncthreads();   // prior iteration's frag reads complete
        *(s8v*)&At[(arow)      * LROW + kc8] = a0;
        *(s8v*)&Bt[(arow)      * LROW + kc8] = b0;
        *(s8v*)&Bt[(arow + 64) * LROW + kc8] = b1;
        __syncthreads();   // tiles ready

        const int k0n = ((s + 1 < NSTEP) ? (s + 1) : s) * 32;
        s8v na0 = *(const s8v*)(pA0 + k0n);
        s8v nb0 = *(const s8v*)(pB0 + k0n);
        s8v nb1 = *(const s8v*)(pB1 + k0n);

        s8v av[2], bv[4];
        #pragma unroll
        for (int f = 0; f < 2; ++f)
            av[f] = *(const s8v*)&At[(wm * 32 + f * 16 + r16) * LROW + g * 8];
        #pragma unroll
        for (int f = 0; f < 4; ++f)
            bv[f] = *(const s8v*)&Bt[(wn * 64 + f * 16 + r16) * LROW + g * 8];
        #pragma unroll
        for (int fm = 0; fm < 2; ++fm)
            #pragma unroll
            for (int fn = 0; fn < 4; ++fn)
                acc[fm][fn] = __builtin_amdgcn_mfma_f32_16x16x32_bf16(
                    av[fm], bv[fn], acc[fm][fn], 0, 0, 0);

        a0 = na0; b0 = nb0; b1 = nb1;
    }

    // Epilogue. D frag: col(n) = lane&15, row(m) = (lane>>4)*4 + reg. (verified)
    float al = 0.f;
    if constexpr (EPI == 0) al = alpha[0];
    #pragma unroll
    for (int fm = 0; fm < 2; ++fm) {
        const int mbase = mb + wm * 32 + fm * 16 + g * 4;
        float4 b4 = *(const float4*)&bias[mbase];
        float bb[4] = { b4.x, b4.y, b4.z, b4.w };
        float sc[4], mn[4], bt[4];
        if constexpr (EPI == 0) {
            float4 g4  = *(const float4*)&gamma[mbase];
            float4 v4  = *(const float4*)&var[mbase];
            float4 m4  = *(const float4*)&mean[mbase];
            float4 be4 = *(const float4*)&beta[mbase];
            sc[0] = g4.x / sqrtf(v4.x + EPSV); sc[1] = g4.y / sqrtf(v4.y + EPSV);
            sc[2] = g4.z / sqrtf(v4.z + EPSV); sc[3] = g4.w / sqrtf(v4.w + EPSV);
            mn[0] = m4.x; mn[1] = m4.y; mn[2] = m4.z; mn[3] = m4.w;
            bt[0] = be4.x; bt[1] = be4.y; bt[2] = be4.z; bt[3] = be4.w;
        }
        #pragma unroll
        for (int fn = 0; fn < 4; ++fn) {
            const int n = nb + wn * 64 + fn * 16 + r16;
            f4v a = acc[fm][fn];
            u4v rv = {};
            if constexpr (EPI == 2) rv = *(const u4v*)&Resid[(size_t)n * MOUT + mbase];
            u4v ro;
            #pragma unroll
            for (int r = 0; r < 4; ++r) {
                float v = a[r] + bb[r];
                if constexpr (EPI == 0) {
                    v = (v > 0.f) ? v : al * v;
                    v = (v - mn[r]) * sc[r] + bt[r];
                }
                if constexpr (EPI == 2) v += bf2f(rv[r]);
                ro[r] = f2bf(v);
            }
            *(u4v*)&OutB[(size_t)n * MOUT + mbase] = ro;
        }
    }
}

// =====================================================================
// Depthwise K=3 dilated conv + bias + PReLU + BN. bf16 [NS][512]. (verified)
// =====================================================================
__global__ __launch_bounds__(256)
void dw_k(const unsigned short* __restrict__ P, const float* __restrict__ wd,
          const float* __restrict__ bd, const float* __restrict__ a2,
          const float* __restrict__ g2, const float* __restrict__ be2,
          const float* __restrict__ m2, const float* __restrict__ v2,
          unsigned short* __restrict__ Q, int dil)
{
    const int t  = threadIdx.x;
    const int d8 = (t & 63) * 8;
    const int n  = blockIdx.x * 4 + (t >> 6);
    const int b  = (n >= TC) ? 1 : 0;
    const int tt = n - b * TC;

    u8v c = *(const u8v*)&P[(size_t)n * 512 + d8];
    u8v l = {}, r = {};
    const bool hasL = (tt - dil >= 0);
    const bool hasR = (tt + dil < TC);
    if (hasL) l = *(const u8v*)&P[(size_t)(n - dil) * 512 + d8];
    if (hasR) r = *(const u8v*)&P[(size_t)(n + dil) * 512 + d8];

    float w24[24];
    #pragma unroll
    for (int q = 0; q < 6; ++q) {
        float4 v = *(const float4*)&wd[d8 * 3 + q * 4];
        w24[q*4+0] = v.x; w24[q*4+1] = v.y; w24[q*4+2] = v.z; w24[q*4+3] = v.w;
    }
    float bdv[8], gv[8], bev[8], mnv[8], vrv[8];
    #pragma unroll
    for (int q = 0; q < 2; ++q) {
        float4 v0 = *(const float4*)&bd[d8 + q*4];
        float4 v1 = *(const float4*)&g2[d8 + q*4];
        float4 v2_ = *(const float4*)&be2[d8 + q*4];
        float4 v3 = *(const float4*)&m2[d8 + q*4];
        float4 v4 = *(const float4*)&v2[d8 + q*4];
        bdv[q*4+0]=v0.x; bdv[q*4+1]=v0.y; bdv[q*4+2]=v0.z; bdv[q*4+3]=v0.w;
        gv [q*4+0]=v1.x; gv [q*4+1]=v1.y; gv [q*4+2]=v1.z; gv [q*4+3]=v1.w;
        bev[q*4+0]=v2_.x;bev[q*4+1]=v2_.y;bev[q*4+2]=v2_.z;bev[q*4+3]=v2_.w;
        mnv[q*4+0]=v3.x; mnv[q*4+1]=v3.y; mnv[q*4+2]=v3.z; mnv[q*4+3]=v3.w;
        vrv[q*4+0]=v4.x; vrv[q*4+1]=v4.y; vrv[q*4+2]=v4.z; vrv[q*4+3]=v4.w;
    }
    const float al = a2[0];

    u8v o;
    #pragma unroll
    for (int i = 0; i < 8; ++i) {
        float acc = bf2f(c[i]) * w24[i*3+1];
        if (hasL) acc = fmaf(bf2f(l[i]), w24[i*3+0], acc);
        if (hasR) acc = fmaf(bf2f(r[i]), w24[i*3+2], acc);
        acc += bdv[i];
        acc = (acc > 0.f) ? acc : al * acc;
        acc = (acc - mnv[i]) * (gv[i] / sqrtf(vrv[i] + EPSV)) + bev[i];
        o[i] = f2bf(acc);
    }
    *(u8v*)&Q[(size_t)n * 512 + d8] = o;
}

// =====================================================================
// mask: masked = enc * sigmoid(H), bf16 [N][E] (verified)
// =====================================================================
#define TOT8 ((ECH * NS) / 8)    // 413696
__global__ __launch_bounds__(256)
void mask_k(const unsigned short* __restrict__ EncB,
            const unsigned short* __restrict__ Hb,
            unsigned short* __restrict__ Mb)
{
    int i = blockIdx.x * 256 + threadIdx.x;
    u8v ev = ((const u8v*)EncB)[i];
    u8v hv = ((const u8v*)Hb)[i];
    u8v o;
    #pragma unroll
    for (int k = 0; k < 8; ++k) {
        float h = bf2f(hv[k]);
        float s = 1.f / (1.f + expf(-h));
        o[k] = f2bf(bf2f(ev[k]) * s);
    }
    ((u8v*)Mb)[i] = o;
}

// =====================================================================
// Decoder on bf16 [N][E] (verified incl. r9 coverage fix)
// =====================================================================
__global__ __launch_bounds__(256)
void decoder_k(const unsigned short* __restrict__ Mb,
               const float* __restrict__ dec_w, const float* __restrict__ db,
               float* __restrict__ out)
{
    __shared__ float wlds[5120];        // [256 e][20 k]
    __shared__ float red[2560];         // [32 t0][8 grp][10 j]
    const int t = threadIdx.x;
    #pragma unroll
    for (int i = 0; i < 5; ++i)
        ((float4*)wlds)[t + i * 256] = ((const float4*)dec_w)[t + i * 256];
    __syncthreads();

    const int grp = t >> 5;             // 0..7
    const int t0l = t & 31;
    const int t0  = blockIdx.x * 32 + t0l;
    const int by  = blockIdx.y;
    const int n0  = by * TC + t0 + 2;
    const int e0  = grp * 32;

    float acc[10];
    #pragma unroll
    for (int j = 0; j < 10; ++j) acc[j] = 0.f;

    #pragma unroll
    for (int q = 0; q < 4; ++q) {
        u8v a0 = *(const u8v*)&Mb[(size_t)n0 * 256 + e0 + q * 8];
        u8v a1 = *(const u8v*)&Mb[(size_t)(n0 - 1) * 256 + e0 + q * 8];
        #pragma unroll
        for (int i = 0; i < 8; ++i) {
            float m0 = bf2f(a0[i]);
            float m1 = bf2f(a1[i]);
            const float* wr = &wlds[(e0 + q * 8 + i) * 20];
            #pragma unroll
            for (int j = 0; j < 10; ++j)
                acc[j] = fmaf(m0, wr[j], fmaf(m1, wr[j + 10], acc[j]));
        }
    }
    #pragma unroll
    for (int j = 0; j < 10; ++j)
        red[(t0l * 8 + grp) * 10 + j] = acc[j];
    __syncthreads();

    for (int s = t; s < 320; s += 256) {          // full coverage (r9 fix)
        int t0l2 = s / 10, j = s - t0l2 * 10;
        float sm = 0.f;
        #pragma unroll
        for (int gq = 0; gq < 8; ++gq) sm += red[(t0l2 * 8 + gq) * 10 + j];
        out[(size_t)by * TLEN + (size_t)(blockIdx.x * 32 + t0l2) * 10 + j] = sm + db[0];
    }
}

// =====================================================================
extern "C" void kernel_launch(void* const* d_in, const int* in_sizes, int n_in,
                              void* d_out, int out_size, void* d_ws, size_t ws_size,
                              hipStream_t stream)
{
    (void)in_sizes; (void)n_in; (void)out_size; (void)ws_size;
    const float* x     = (const float*)d_in[0];
    const float* enc_w = (const float*)d_in[1];
    const float* enc_b = (const float*)d_in[2];
    const float* w1    = (const float*)d_in[3];
    const float* b1    = (const float*)d_in[4];
    const float* a1    = (const float*)d_in[5];
    const float* g1    = (const float*)d_in[6];
    const float* be1   = (const float*)d_in[7];
    const float* m1    = (const float*)d_in[8];
    const float* v1    = (const float*)d_in[9];
    const float* wd    = (const float*)d_in[10];
    const float* bd    = (const float*)d_in[11];
    const float* a2    = (const float*)d_in[12];
    const float* g2    = (const float*)d_in[13];
    const float* be2   = (const float*)d_in[14];
    const float* m2    = (const float*)d_in[15];
    const float* v2    = (const float*)d_in[16];
    const float* w2    = (const float*)d_in[17];
    const float* b2    = (const float*)d_in[18];
    const float* dec_w = (const float*)d_in[19];
    const float* dec_b = (const float*)d_in[20];
    float* out = (float*)d_out;

    // ---- workspace carve-up (all bf16 activations, [N][C] layouts) ----
    const size_t B_EN = (size_t)NS * 256 * 2;      //  6,619,136
    const size_t B_DN = (size_t)NS * 512 * 2;      // 13,238,272
    char* p = (char*)d_ws;
    unsigned short* Hb   = (unsigned short*)p;  p += B_EN;   // block input / residual
    unsigned short* Hb2  = (unsigned short*)p;  p += B_EN;   // intra-block H
    unsigned short* EncB = (unsigned short*)p;  p += B_EN;
    unsigned short* Pb   = (unsigned short*)p;  p += B_DN;
    unsigned short* Qb   = (unsigned short*)p;  p += B_DN;
    unsigned short* w1b  = (unsigned short*)p;  p += (size_t)12*512*256*2;
    unsigned short* w2b  = (unsigned short*)p;
    unsigned short* Mb   = Pb;   // reuse after separator

    dim3 blk(256);
    wcvt_k<<<dim3(2 * NWQ / 256), blk, 0, stream>>>(w1, w2, w1b, w2b);
    encoder_k<<<dim3(101, 2), blk, 0, stream>>>(x, enc_w, enc_b, EncB, Hb);

    for (int bI = 0; bI < NBLK; ++bI) {
        for (int i = 0; i < NLAY; ++i) {
            const int li  = bI * NLAY + i;
            const int dil = 1 << i;
            // conv1: E->D (bias+PReLU+BN); layer0 reads block input Hb, else Hb2
            const unsigned short* hin = (i == 0) ? Hb : Hb2;
            gemm_bf16_k<ECH, DCH, 0><<<dim3(NTILE, DCH / 64), blk, 0, stream>>>(
                w1b + (size_t)li * DCH * ECH, hin, Pb,
                b1 + (size_t)li * DCH, a1 + li,
                g1 + (size_t)li * DCH, be1 + (size_t)li * DCH,
                m1 + (size_t)li * DCH, v1 + (size_t)li * DCH, nullptr);
            // depthwise
            dw_k<<<dim3(NS / 4), blk, 0, stream>>>(
                Pb, wd + (size_t)li * DCH * 3, bd + (size_t)li * DCH, a2 + li,
                g2 + (size_t)li * DCH, be2 + (size_t)li * DCH,
                m2 + (size_t)li * DCH, v2 + (size_t)li * DCH, Qb, dil);
            // conv2: D->E; block-end adds residual (Hb) and writes Hb in-place
            if (i == NLAY - 1) {
                gemm_bf16_k<DCH, ECH, 2><<<dim3(NTILE, ECH / 64), blk, 0, stream>>>(
                    w2b + (size_t)li * ECH * DCH, Qb, Hb,
                    b2 + (size_t)li * ECH, nullptr, nullptr, nullptr,
                    nullptr, nullptr, Hb);
            } else {
                gemm_bf16_k<DCH, ECH, 1><<<dim3(NTILE, ECH / 64), blk, 0, stream>>>(
                    w2b + (size_t)li * ECH * DCH, Qb, Hb2,
                    b2 + (size_t)li * ECH, nullptr, nullptr, nullptr,
                    nullptr, nullptr, nullptr);
            }
        }
    }

    mask_k<<<dim3(TOT8 / 256), blk, 0, stream>>>(EncB, Hb, Mb);
    decoder_k<<<dim3(200, 2), blk, 0, stream>>>(Mb, dec_w, dec_b, out);
}

// Round 11
// 641.201 us; speedup vs baseline: 1.1142x; 1.1142x over previous
//
#include <hip/hip_runtime.h>
#include <math.h>

// ---------------- problem constants ----------------
#define TLEN   64000
#define ECH    256
#define DCH    512
#define NBLK   2
#define NLAY   6
#define FKC    20
#define STRIDE_ 10
#define TC     6403            // encoder output length
#define NS     12928           // padded row count = 101*128 (n = b*TC + tc)
#define NTILE  101             // NS / 128
#define EPSV   1e-5f

typedef __attribute__((ext_vector_type(8))) short          s8v;
typedef __attribute__((ext_vector_type(4))) float          f4v;
typedef __attribute__((ext_vector_type(4))) unsigned short u4v;
typedef __attribute__((ext_vector_type(8))) unsigned short u8v;

__device__ __forceinline__ unsigned short f2bf(float f) {
    union { float f; unsigned u; } v; v.f = f;
    unsigned r = v.u + 0x7FFFu + ((v.u >> 16) & 1u);   // RNE
    return (unsigned short)(r >> 16);
}
__device__ __forceinline__ float bf2f(unsigned short h) {
    union { unsigned u; float f; } v; v.u = ((unsigned)h) << 16; return v.f;
}

// =====================================================================
// Weight convert fp32 -> bf16 (verified)
// =====================================================================
#define NWQ (12*512*256/4)      // float4 count per tensor = 393216
__global__ __launch_bounds__(256)
void wcvt_k(const float* __restrict__ w1, const float* __restrict__ w2,
            unsigned short* __restrict__ w1b, unsigned short* __restrict__ w2b)
{
    int i = blockIdx.x * 256 + threadIdx.x;
    if (i < NWQ) {
        float4 v = ((const float4*)w1)[i];
        u4v o = { f2bf(v.x), f2bf(v.y), f2bf(v.z), f2bf(v.w) };
        ((u4v*)w1b)[i] = o;
    } else {
        int j = i - NWQ;
        float4 v = ((const float4*)w2)[j];
        u4v o = { f2bf(v.x), f2bf(v.y), f2bf(v.z), f2bf(v.w) };
        ((u4v*)w2b)[j] = o;
    }
}

// =====================================================================
// Encoder -> bf16 [N][E] directly (verified)
// =====================================================================
__global__ __launch_bounds__(256)
void encoder_k(const float* __restrict__ x, const float* __restrict__ ew,
               const float* __restrict__ eb,
               unsigned short* __restrict__ EncB, unsigned short* __restrict__ Hb)
{
    __shared__ float xs[660];
    const int bx  = blockIdx.x;      // 0..100
    const int b   = blockIdx.y;      // 0..1
    const int tc0 = bx * 64;
    const int base_g = tc0 * STRIDE_ - FKC;
    for (int i = threadIdx.x; i < 660; i += 256) {
        int idx = base_g + i;
        xs[i] = (idx >= 0 && idx < TLEN) ? x[b * TLEN + idx] : 0.f;
    }
    __syncthreads();

    const int e = threadIdx.x;
    float w[20];
    #pragma unroll
    for (int q = 0; q < 5; ++q) {
        float4 v = *(const float4*)&ew[e * 20 + q * 4];
        w[q*4+0] = v.x; w[q*4+1] = v.y; w[q*4+2] = v.z; w[q*4+3] = v.w;
    }
    const float bz = eb[e];
    const int jmax = (TC - tc0 < 64) ? (TC - tc0) : 64;
    for (int j = 0; j < jmax; ++j) {
        const float* xp = &xs[j * 10];
        float acc = bz;
        #pragma unroll
        for (int k = 0; k < 20; ++k) acc = fmaf(xp[k], w[k], acc);
        unsigned short hv = f2bf(acc);
        size_t o = (size_t)(b * TC + tc0 + j) * 256 + e;
        EncB[o] = hv;
        Hb[o]   = hv;
    }
}

// =====================================================================
// bf16 MFMA GEMM, 128x128 tile (r9 geometry, verified), staging via
// global_load_lds width-16 into LINEAR LDS (LROW=32, no pad — required:
// gload_lds writes wave-uniform base + lane*16; m97 structure).
//   acc[n][m] = sum_k W[m][k] * Act[n][k];  Out bf16 [NS][MOUT]
// EPI 0: bias+PReLU+BN | 1: bias | 2: bias+resid (in-place safe)
// =====================================================================
template<int KD, int MOUT, int EPI>
__global__ __launch_bounds__(256)
void gemm_bf16_k(const unsigned short* __restrict__ Wb,
                 const unsigned short* __restrict__ Act,
                 unsigned short* __restrict__ OutB,
                 const float* __restrict__ bias,
                 const float* __restrict__ alpha,
                 const float* __restrict__ gamma,
                 const float* __restrict__ beta,
                 const float* __restrict__ mean,
                 const float* __restrict__ var,
                 const unsigned short* __restrict__ Resid)
{
    __shared__ short At[128 * 32];     // [m][k], 64 B/row
    __shared__ short Bt[128 * 32];     // [n][k]

    const int t    = threadIdx.x;
    const int lane = t & 63;
    const int wid  = t >> 6;
    const int wm   = wid >> 1, wn = wid & 1;
    const int r16  = lane & 15, g = lane >> 4;
    const int mb   = blockIdx.y * 128;
    const int nb   = blockIdx.x * 128;

    f4v acc[4][4];
    #pragma unroll
    for (int a = 0; a < 4; ++a)
        #pragma unroll
        for (int c = 0; c < 4; ++c)
            acc[a][c] = (f4v){0.f, 0.f, 0.f, 0.f};

    const char* gA = (const char*)Wb;
    const char* gB = (const char*)Act;
    char* lA = (char*)At;
    char* lB = (char*)Bt;

    for (int k0 = 0; k0 < KD; k0 += 32) {
        // stage A and B tiles: 512 x 16B chunks each, 2 per thread.
        // chunk ch -> row ch>>2, 16B piece ch&3. Dest: wave-uniform base
        // (i*4096 + wid*1024) + lane*16 (HW) == row (i*64+wid*16+lane>>2).
        #pragma unroll
        for (int i = 0; i < 2; ++i) {
            int ch = i * 256 + t;
            const char* srcA = gA + ((size_t)(mb + (ch >> 2)) * KD + k0) * 2 + (ch & 3) * 16;
            __builtin_amdgcn_global_load_lds(
                (const __attribute__((address_space(1))) void*)srcA,
                (__attribute__((address_space(3))) void*)(lA + i * 4096 + wid * 1024),
                16, 0, 0);
            const char* srcB = gB + ((size_t)(nb + (ch >> 2)) * KD + k0) * 2 + (ch & 3) * 16;
            __builtin_amdgcn_global_load_lds(
                (const __attribute__((address_space(1))) void*)srcB,
                (__attribute__((address_space(3))) void*)(lB + i * 4096 + wid * 1024),
                16, 0, 0);
        }
        __syncthreads();   // drains vmcnt(0) before barrier -> tiles ready

        s8v av[4], bv[4];
        #pragma unroll
        for (int f = 0; f < 4; ++f) {
            av[f] = *(const s8v*)&At[(wm * 64 + f * 16 + r16) * 32 + g * 8];
            bv[f] = *(const s8v*)&Bt[(wn * 64 + f * 16 + r16) * 32 + g * 8];
        }
        #pragma unroll
        for (int fm = 0; fm < 4; ++fm)
            #pragma unroll
            for (int fn = 0; fn < 4; ++fn)
                acc[fm][fn] = __builtin_amdgcn_mfma_f32_16x16x32_bf16(
                    av[fm], bv[fn], acc[fm][fn], 0, 0, 0);
        __syncthreads();   // reads done before next stage overwrites
    }

    // Epilogue. D frag: col(n) = lane&15, row(m) = (lane>>4)*4 + reg. (verified)
    float al = 0.f;
    if constexpr (EPI == 0) al = alpha[0];
    #pragma unroll
    for (int fm = 0; fm < 4; ++fm) {
        const int mbase = mb + wm * 64 + fm * 16 + g * 4;
        float4 b4 = *(const float4*)&bias[mbase];
        float bb[4] = { b4.x, b4.y, b4.z, b4.w };
        float sc[4], mn[4], bt[4];
        if constexpr (EPI == 0) {
            float4 g4  = *(const float4*)&gamma[mbase];
            float4 v4  = *(const float4*)&var[mbase];
            float4 m4  = *(const float4*)&mean[mbase];
            float4 be4 = *(const float4*)&beta[mbase];
            sc[0] = g4.x / sqrtf(v4.x + EPSV); sc[1] = g4.y / sqrtf(v4.y + EPSV);
            sc[2] = g4.z / sqrtf(v4.z + EPSV); sc[3] = g4.w / sqrtf(v4.w + EPSV);
            mn[0] = m4.x; mn[1] = m4.y; mn[2] = m4.z; mn[3] = m4.w;
            bt[0] = be4.x; bt[1] = be4.y; bt[2] = be4.z; bt[3] = be4.w;
        }
        #pragma unroll
        for (int fn = 0; fn < 4; ++fn) {
            const int n = nb + wn * 64 + fn * 16 + r16;
            f4v a = acc[fm][fn];
            u4v rv = {};
            if constexpr (EPI == 2) rv = *(const u4v*)&Resid[(size_t)n * MOUT + mbase];
            u4v ro;
            #pragma unroll
            for (int r = 0; r < 4; ++r) {
                float v = a[r] + bb[r];
                if constexpr (EPI == 0) {
                    v = (v > 0.f) ? v : al * v;
                    v = (v - mn[r]) * sc[r] + bt[r];
                }
                if constexpr (EPI == 2) v += bf2f(rv[r]);
                ro[r] = f2bf(v);
            }
            *(u4v*)&OutB[(size_t)n * MOUT + mbase] = ro;
        }
    }
}

// =====================================================================
// Depthwise K=3 dilated conv + bias + PReLU + BN. bf16 [NS][512]. (verified)
// =====================================================================
__global__ __launch_bounds__(256)
void dw_k(const unsigned short* __restrict__ P, const float* __restrict__ wd,
          const float* __restrict__ bd, const float* __restrict__ a2,
          const float* __restrict__ g2, const float* __restrict__ be2,
          const float* __restrict__ m2, const float* __restrict__ v2,
          unsigned short* __restrict__ Q, int dil)
{
    const int t  = threadIdx.x;
    const int d8 = (t & 63) * 8;
    const int n  = blockIdx.x * 4 + (t >> 6);
    const int b  = (n >= TC) ? 1 : 0;
    const int tt = n - b * TC;

    u8v c = *(const u8v*)&P[(size_t)n * 512 + d8];
    u8v l = {}, r = {};
    const bool hasL = (tt - dil >= 0);
    const bool hasR = (tt + dil < TC);
    if (hasL) l = *(const u8v*)&P[(size_t)(n - dil) * 512 + d8];
    if (hasR) r = *(const u8v*)&P[(size_t)(n + dil) * 512 + d8];

    float w24[24];
    #pragma unroll
    for (int q = 0; q < 6; ++q) {
        float4 v = *(const float4*)&wd[d8 * 3 + q * 4];
        w24[q*4+0] = v.x; w24[q*4+1] = v.y; w24[q*4+2] = v.z; w24[q*4+3] = v.w;
    }
    float bdv[8], gv[8], bev[8], mnv[8], vrv[8];
    #pragma unroll
    for (int q = 0; q < 2; ++q) {
        float4 v0 = *(const float4*)&bd[d8 + q*4];
        float4 v1 = *(const float4*)&g2[d8 + q*4];
        float4 v2_ = *(const float4*)&be2[d8 + q*4];
        float4 v3 = *(const float4*)&m2[d8 + q*4];
        float4 v4 = *(const float4*)&v2[d8 + q*4];
        bdv[q*4+0]=v0.x; bdv[q*4+1]=v0.y; bdv[q*4+2]=v0.z; bdv[q*4+3]=v0.w;
        gv [q*4+0]=v1.x; gv [q*4+1]=v1.y; gv [q*4+2]=v1.z; gv [q*4+3]=v1.w;
        bev[q*4+0]=v2_.x;bev[q*4+1]=v2_.y;bev[q*4+2]=v2_.z;bev[q*4+3]=v2_.w;
        mnv[q*4+0]=v3.x; mnv[q*4+1]=v3.y; mnv[q*4+2]=v3.z; mnv[q*4+3]=v3.w;
        vrv[q*4+0]=v4.x; vrv[q*4+1]=v4.y; vrv[q*4+2]=v4.z; vrv[q*4+3]=v4.w;
    }
    const float al = a2[0];

    u8v o;
    #pragma unroll
    for (int i = 0; i < 8; ++i) {
        float acc = bf2f(c[i]) * w24[i*3+1];
        if (hasL) acc = fmaf(bf2f(l[i]), w24[i*3+0], acc);
        if (hasR) acc = fmaf(bf2f(r[i]), w24[i*3+2], acc);
        acc += bdv[i];
        acc = (acc > 0.f) ? acc : al * acc;
        acc = (acc - mnv[i]) * (gv[i] / sqrtf(vrv[i] + EPSV)) + bev[i];
        o[i] = f2bf(acc);
    }
    *(u8v*)&Q[(size_t)n * 512 + d8] = o;
}

// =====================================================================
// mask: masked = enc * sigmoid(H), bf16 [N][E] (verified)
// =====================================================================
#define TOT8 ((ECH * NS) / 8)    // 413696
__global__ __launch_bounds__(256)
void mask_k(const unsigned short* __restrict__ EncB,
            const unsigned short* __restrict__ Hb,
            unsigned short* __restrict__ Mb)
{
    int i = blockIdx.x * 256 + threadIdx.x;
    u8v ev = ((const u8v*)EncB)[i];
    u8v hv = ((const u8v*)Hb)[i];
    u8v o;
    #pragma unroll
    for (int k = 0; k < 8; ++k) {
        float h = bf2f(hv[k]);
        float s = 1.f / (1.f + expf(-h));
        o[k] = f2bf(bf2f(ev[k]) * s);
    }
    ((u8v*)Mb)[i] = o;
}

// =====================================================================
// Decoder on bf16 [N][E] (verified incl. r9 coverage fix)
// =====================================================================
__global__ __launch_bounds__(256)
void decoder_k(const unsigned short* __restrict__ Mb,
               const float* __restrict__ dec_w, const float* __restrict__ db,
               float* __restrict__ out)
{
    __shared__ float wlds[5120];        // [256 e][20 k]
    __shared__ float red[2560];         // [32 t0][8 grp][10 j]
    const int t = threadIdx.x;
    #pragma unroll
    for (int i = 0; i < 5; ++i)
        ((float4*)wlds)[t + i * 256] = ((const float4*)dec_w)[t + i * 256];
    __syncthreads();

    const int grp = t >> 5;             // 0..7
    const int t0l = t & 31;
    const int t0  = blockIdx.x * 32 + t0l;
    const int by  = blockIdx.y;
    const int n0  = by * TC + t0 + 2;
    const int e0  = grp * 32;

    float acc[10];
    #pragma unroll
    for (int j = 0; j < 10; ++j) acc[j] = 0.f;

    #pragma unroll
    for (int q = 0; q < 4; ++q) {
        u8v a0 = *(const u8v*)&Mb[(size_t)n0 * 256 + e0 + q * 8];
        u8v a1 = *(const u8v*)&Mb[(size_t)(n0 - 1) * 256 + e0 + q * 8];
        #pragma unroll
        for (int i = 0; i < 8; ++i) {
            float m0 = bf2f(a0[i]);
            float m1 = bf2f(a1[i]);
            const float* wr = &wlds[(e0 + q * 8 + i) * 20];
            #pragma unroll
            for (int j = 0; j < 10; ++j)
                acc[j] = fmaf(m0, wr[j], fmaf(m1, wr[j + 10], acc[j]));
        }
    }
    #pragma unroll
    for (int j = 0; j < 10; ++j)
        red[(t0l * 8 + grp) * 10 + j] = acc[j];
    __syncthreads();

    for (int s = t; s < 320; s += 256) {          // full coverage (r9 fix)
        int t0l2 = s / 10, j = s - t0l2 * 10;
        float sm = 0.f;
        #pragma unroll
        for (int gq = 0; gq < 8; ++gq) sm += red[(t0l2 * 8 + gq) * 10 + j];
        out[(size_t)by * TLEN + (size_t)(blockIdx.x * 32 + t0l2) * 10 + j] = sm + db[0];
    }
}

// =====================================================================
extern "C" void kernel_launch(void* const* d_in, const int* in_sizes, int n_in,
                              void* d_out, int out_size, void* d_ws, size_t ws_size,
                              hipStream_t stream)
{
    (void)in_sizes; (void)n_in; (void)out_size; (void)ws_size;
    const float* x     = (const float*)d_in[0];
    const float* enc_w = (const float*)d_in[1];
    const float* enc_b = (const float*)d_in[2];
    const float* w1    = (const float*)d_in[3];
    const float* b1    = (const float*)d_in[4];
    const float* a1    = (const float*)d_in[5];
    const float* g1    = (const float*)d_in[6];
    const float* be1   = (const float*)d_in[7];
    const float* m1    = (const float*)d_in[8];
    const float* v1    = (const float*)d_in[9];
    const float* wd    = (const float*)d_in[10];
    const float* bd    = (const float*)d_in[11];
    const float* a2    = (const float*)d_in[12];
    const float* g2    = (const float*)d_in[13];
    const float* be2   = (const float*)d_in[14];
    const float* m2    = (const float*)d_in[15];
    const float* v2    = (const float*)d_in[16];
    const float* w2    = (const float*)d_in[17];
    const float* b2    = (const float*)d_in[18];
    const float* dec_w = (const float*)d_in[19];
    const float* dec_b = (const float*)d_in[20];
    float* out = (float*)d_out;

    // ---- workspace carve-up (all bf16 activations, [N][C] layouts) ----
    const size_t B_EN = (size_t)NS * 256 * 2;      //  6,619,136
    const size_t B_DN = (size_t)NS * 512 * 2;      // 13,238,272
    char* p = (char*)d_ws;
    unsigned short* Hb   = (unsigned short*)p;  p += B_EN;   // block input / residual
    unsigned short* Hb2  = (unsigned short*)p;  p += B_EN;   // intra-block H
    unsigned short* EncB = (unsigned short*)p;  p += B_EN;
    unsigned short* Pb   = (unsigned short*)p;  p += B_DN;
    unsigned short* Qb   = (unsigned short*)p;  p += B_DN;
    unsigned short* w1b  = (unsigned short*)p;  p += (size_t)12*512*256*2;
    unsigned short* w2b  = (unsigned short*)p;
    unsigned short* Mb   = Pb;   // reuse after separator

    dim3 blk(256);
    wcvt_k<<<dim3(2 * NWQ / 256), blk, 0, stream>>>(w1, w2, w1b, w2b);
    encoder_k<<<dim3(101, 2), blk, 0, stream>>>(x, enc_w, enc_b, EncB, Hb);

    for (int bI = 0; bI < NBLK; ++bI) {
        for (int i = 0; i < NLAY; ++i) {
            const int li  = bI * NLAY + i;
            const int dil = 1 << i;
            // conv1: E->D (bias+PReLU+BN); layer0 reads block input Hb, else Hb2
            const unsigned short* hin = (i == 0) ? Hb : Hb2;
            gemm_bf16_k<ECH, DCH, 0><<<dim3(NTILE, DCH / 128), blk, 0, stream>>>(
                w1b + (size_t)li * DCH * ECH, hin, Pb,
                b1 + (size_t)li * DCH, a1 + li,
                g1 + (size_t)li * DCH, be1 + (size_t)li * DCH,
                m1 + (size_t)li * DCH, v1 + (size_t)li * DCH, nullptr);
            // depthwise
            dw_k<<<dim3(NS / 4), blk, 0, stream>>>(
                Pb, wd + (size_t)li * DCH * 3, bd + (size_t)li * DCH, a2 + li,
                g2 + (size_t)li * DCH, be2 + (size_t)li * DCH,
                m2 + (size_t)li * DCH, v2 + (size_t)li * DCH, Qb, dil);
            // conv2: D->E; block-end adds residual (Hb) and writes Hb in-place
            if (i == NLAY - 1) {
                gemm_bf16_k<DCH, ECH, 2><<<dim3(NTILE, ECH / 128), blk, 0, stream>>>(
                    w2b + (size_t)li * ECH * DCH, Qb, Hb,
                    b2 + (size_t)li * ECH, nullptr, nullptr, nullptr,
                    nullptr, nullptr, Hb);
            } else {
                gemm_bf16_k<DCH, ECH, 1><<<dim3(NTILE, ECH / 128), blk, 0, stream>>>(
                    w2b + (size_t)li * ECH * DCH, Qb, Hb2,
                    b2 + (size_t)li * ECH, nullptr, nullptr, nullptr,
                    nullptr, nullptr, nullptr);
            }
        }
    }

    mask_k<<<dim3(TOT8 / 256), blk, 0, stream>>>(EncB, Hb, Mb);
    decoder_k<<<dim3(200, 2), blk, 0, stream>>>(Mb, dec_w, dec_b, out);
}